// Round 1
// baseline (3427.082 us; speedup 1.0000x reference)
//
#include <hip/hip_runtime.h>
#include <hip/hip_bf16.h>
#include <math.h>

// Problem constants (from reference)
#define NN 100000      // nodes
#define NE 1600000     // edges
#define NF 256         // input features
#define NH 128         // hidden
#define NC 40          // classes

// Workspace layout (floats):
//   dinv  : [0, NN)
//   H     : [OFF_H, OFF_H + NN*NH)          -- x@W1, later reused: H2 (NN*NC) + H2agg (NN*NC)
//   Hagg  : [OFF_HAGG, OFF_HAGG + NN*NH)
#define OFF_H    100032                       // 100000 rounded up to mult of 64 (16B aligned)
#define OFF_HAGG (OFF_H + (size_t)NN * NH)

// ---------------- degree ----------------
__global__ void deg_kernel(const int* __restrict__ dst, float* __restrict__ deg) {
    int t = blockIdx.x * blockDim.x + threadIdx.x;
    if (t < NE) atomicAdd(&deg[dst[t]], 1.0f);
}

__global__ void rsqrt_kernel(float* __restrict__ deg) {
    int t = blockIdx.x * blockDim.x + threadIdx.x;
    if (t < NN) deg[t] = rsqrtf(deg[t] + 1.0f);   // +1 self loop; deg>=1 always
}

// ---------------- simple register-tiled fp32 GEMM ----------------
// C[M,N] = A[M,K] @ B[K,N]; K % BK == 0
template<int BM, int BN, int BK, int TM, int TN>
__global__ void gemm_f32(const float* __restrict__ A, const float* __restrict__ B,
                         float* __restrict__ C, int M, int N, int K) {
    constexpr int THREADS = (BM / TM) * (BN / TN);
    __shared__ float sA[BK][BM + 1];
    __shared__ float sB[BK][BN];
    const int tid  = threadIdx.x;
    const int tcol = tid % (BN / TN);
    const int trow = tid / (BN / TN);
    const int row0 = blockIdx.y * BM;
    const int col0 = blockIdx.x * BN;

    float acc[TM][TN];
    #pragma unroll
    for (int i = 0; i < TM; ++i)
        #pragma unroll
        for (int j = 0; j < TN; ++j) acc[i][j] = 0.f;

    for (int k0 = 0; k0 < K; k0 += BK) {
        #pragma unroll
        for (int idx = tid; idx < BM * BK; idx += THREADS) {
            int m = idx / BK, kk = idx % BK;
            int r = row0 + m;
            sA[kk][m] = (r < M) ? A[(size_t)r * K + k0 + kk] : 0.f;
        }
        #pragma unroll
        for (int idx = tid; idx < BK * BN; idx += THREADS) {
            int kk = idx / BN, n = idx % BN;
            int c = col0 + n;
            sB[kk][n] = (c < N) ? B[(size_t)(k0 + kk) * N + c] : 0.f;
        }
        __syncthreads();
        #pragma unroll
        for (int kk = 0; kk < BK; ++kk) {
            float a[TM], b[TN];
            #pragma unroll
            for (int i = 0; i < TM; ++i) a[i] = sA[kk][trow * TM + i];
            #pragma unroll
            for (int j = 0; j < TN; ++j) b[j] = sB[kk][tcol * TN + j];
            #pragma unroll
            for (int i = 0; i < TM; ++i)
                #pragma unroll
                for (int j = 0; j < TN; ++j) acc[i][j] += a[i] * b[j];
        }
        __syncthreads();
    }

    #pragma unroll
    for (int i = 0; i < TM; ++i) {
        int r = row0 + trow * TM + i;
        if (r >= M) continue;
        #pragma unroll
        for (int j = 0; j < TN; ++j) {
            int c = col0 + tcol * TN + j;
            if (c < N) C[(size_t)r * N + c] = acc[i][j];
        }
    }
}

// ---------------- layer-1 scatter: Hagg[dst] += H[src] * norm ----------------
// 32 threads per edge, float4 per thread (128 feats)
__global__ void agg1_kernel(const int* __restrict__ ei, const float* __restrict__ dinv,
                            const float* __restrict__ H, float* __restrict__ Hagg) {
    int t = blockIdx.x * blockDim.x + threadIdx.x;
    int e = t >> 5;
    if (e >= NE) return;
    int lane = t & 31;
    int s = ei[e];
    int d = ei[NE + e];
    float w = dinv[s] * dinv[d];
    const float4* Hs = reinterpret_cast<const float4*>(H + (size_t)s * NH);
    float4 v = Hs[lane];
    float* p = Hagg + (size_t)d * NH + lane * 4;
    atomicAdd(p + 0, v.x * w);
    atomicAdd(p + 1, v.y * w);
    atomicAdd(p + 2, v.z * w);
    atomicAdd(p + 3, v.w * w);
}

// ---------------- bias + self-loop + ReLU (in place on Hagg) ----------------
__global__ void relu_kernel(float* __restrict__ Hagg, const float* __restrict__ H,
                            const float* __restrict__ dinv, const float* __restrict__ b1) {
    int t = blockIdx.x * blockDim.x + threadIdx.x;
    if (t >= NN * NH) return;
    int i = t >> 7;        // /128
    int j = t & 127;
    float di = dinv[i];
    Hagg[t] = fmaxf(Hagg[t] + H[t] * di * di + b1[j], 0.f);
}

// ---------------- layer-2 scatter: H2agg[dst] += H2[src] * norm ----------------
__global__ void agg2_kernel(const int* __restrict__ ei, const float* __restrict__ dinv,
                            const float* __restrict__ H2, float* __restrict__ H2agg) {
    int p = blockIdx.x * blockDim.x + threadIdx.x;
    if (p >= NE * NC) return;
    int e = p / NC;
    int j = p - e * NC;
    int s = ei[e];
    int d = ei[NE + e];
    float w = dinv[s] * dinv[d];
    atomicAdd(&H2agg[(size_t)d * NC + j], H2[(size_t)s * NC + j] * w);
}

// ---------------- bias + self-loop + log_softmax, one wave per row ----------------
__global__ void lsm_kernel(const float* __restrict__ H2agg, const float* __restrict__ H2,
                           const float* __restrict__ dinv, const float* __restrict__ b2,
                           float* __restrict__ out) {
    int wave = threadIdx.x >> 6;
    int lane = threadIdx.x & 63;
    int i = blockIdx.x * 4 + wave;
    if (i >= NN) return;
    float di = dinv[i];
    float v = -INFINITY;
    if (lane < NC)
        v = H2agg[(size_t)i * NC + lane] + H2[(size_t)i * NC + lane] * di * di + b2[lane];
    float m = v;
    #pragma unroll
    for (int off = 32; off; off >>= 1) m = fmaxf(m, __shfl_xor(m, off, 64));
    float ex = (lane < NC) ? expf(v - m) : 0.f;
    #pragma unroll
    for (int off = 32; off; off >>= 1) ex += __shfl_xor(ex, off, 64);
    float ls = logf(ex);
    if (lane < NC) out[(size_t)i * NC + lane] = v - m - ls;
}

extern "C" void kernel_launch(void* const* d_in, const int* in_sizes, int n_in,
                              void* d_out, int out_size, void* d_ws, size_t ws_size,
                              hipStream_t stream) {
    const float* x  = (const float*)d_in[0];
    const int*   ei = (const int*)d_in[1];    // [2, NE] int32: src row then dst row
    const float* W1 = (const float*)d_in[2];
    const float* b1 = (const float*)d_in[3];
    const float* W2 = (const float*)d_in[4];
    const float* b2 = (const float*)d_in[5];
    float* out = (float*)d_out;
    float* ws  = (float*)d_ws;

    float* dinv  = ws;
    float* H     = ws + OFF_H;
    float* Hagg  = ws + OFF_HAGG;
    float* H2    = H;                           // reuse H region after relu
    float* H2agg = H + (size_t)NN * NC;         // also inside old H region

    // 1. degree -> dinv
    hipMemsetAsync(dinv, 0, NN * sizeof(float), stream);
    hipMemsetAsync(Hagg, 0, (size_t)NN * NH * sizeof(float), stream);
    deg_kernel<<<(NE + 255) / 256, 256, 0, stream>>>(ei + NE, dinv);
    rsqrt_kernel<<<(NN + 255) / 256, 256, 0, stream>>>(dinv);

    // 2. H = x @ W1
    {
        dim3 grid((NH + 63) / 64, (NN + 63) / 64);
        gemm_f32<64, 64, 16, 4, 4><<<grid, 256, 0, stream>>>(x, W1, H, NN, NH, NF);
    }

    // 3. scatter layer 1
    {
        long long threads = (long long)NE * 32;
        agg1_kernel<<<(unsigned)((threads + 255) / 256), 256, 0, stream>>>(ei, dinv, H, Hagg);
    }

    // 4. bias + self loop + relu
    relu_kernel<<<(NN * NH + 255) / 256, 256, 0, stream>>>(Hagg, H, dinv, b1);

    // 5. H2 = Hagg @ W2   (writes into reused H region; relu already consumed H)
    {
        dim3 grid((NC + 63) / 64, (NN + 63) / 64);
        gemm_f32<64, 64, 16, 4, 4><<<grid, 256, 0, stream>>>(Hagg, W2, H2, NN, NC, NH);
    }

    // 6. scatter layer 2
    hipMemsetAsync(H2agg, 0, (size_t)NN * NC * sizeof(float), stream);
    {
        long long threads = (long long)NE * NC;
        agg2_kernel<<<(unsigned)((threads + 255) / 256), 256, 0, stream>>>(ei, dinv, H2, H2agg);
    }

    // 7. bias + self loop + log_softmax
    lsm_kernel<<<(NN + 3) / 4, 256, 0, stream>>>(H2agg, H2, dinv, b2, out);
}

// Round 2
// 1014.884 us; speedup vs baseline: 3.3768x; 3.3768x over previous
//
#include <hip/hip_runtime.h>
#include <hip/hip_bf16.h>
#include <math.h>

#define NN 100000      // nodes
#define NE 1600000     // edges
#define NF 256         // input features
#define NH 128         // hidden
#define NC 40          // classes

// Workspace layout (4-byte units):
//   counts  [0,       100032)
//   offsets [100032,  200128)   (NN+1 used)
//   cursor  [200128,  300160)
//   dinv    [300160,  400192)
//   erec    [400192,  3600192)  (NE int2 = 3.2M ints, 8B aligned: 400192*4 % 8 == 0)
//   H       [3600192, 16400192) (NN*NH floats; reused as H2 [NN*NC] after agg1)
//   Hagg    [16400192,29200192) (NN*NH floats)
#define OFF_OFFSETS 100032
#define OFF_CURSOR  200128
#define OFF_DINV    300160
#define OFF_EREC    400192
#define OFF_H       3600192
#define OFF_HAGG    16400192

// ---------------- CSR build ----------------
__global__ void count_kernel(const int* __restrict__ dst, int* __restrict__ count) {
    int t = blockIdx.x * blockDim.x + threadIdx.x;
    if (t < NE) atomicAdd(&count[dst[t]], 1);
}

__global__ void dinv_kernel(const int* __restrict__ count, float* __restrict__ dinv) {
    int t = blockIdx.x * blockDim.x + threadIdx.x;
    if (t < NN) dinv[t] = rsqrtf((float)count[t] + 1.0f);  // +1 self loop
}

// single-block exclusive scan of counts -> offsets (and cursor copy)
__global__ void scan_kernel(const int* __restrict__ count, int* __restrict__ offsets,
                            int* __restrict__ cursor) {
    constexpr int T = 1024;
    constexpr int CHUNK = (NN + T - 1) / T;   // 98
    __shared__ int sums[T];
    const int t = threadIdx.x;
    const int lo = t * CHUNK;
    const int hi = (lo + CHUNK < NN) ? lo + CHUNK : NN;
    int s = 0;
    for (int i = lo; i < hi; ++i) s += count[i];
    sums[t] = s;
    __syncthreads();
    for (int off = 1; off < T; off <<= 1) {
        int v = (t >= off) ? sums[t - off] : 0;
        __syncthreads();
        if (t >= off) sums[t] += v;
        __syncthreads();
    }
    int run = sums[t] - s;   // exclusive prefix of this thread's chunk
    for (int i = lo; i < hi; ++i) {
        offsets[i] = run;
        cursor[i]  = run;
        run += count[i];
    }
    if (t == T - 1) offsets[NN] = run;   // last chunk empty -> run == grand total
}

// counting-sort edges into dst buckets; record (src, weight)
__global__ void bucket_kernel(const int* __restrict__ ei, const float* __restrict__ dinv,
                              int* __restrict__ cursor, int2* __restrict__ erec) {
    int t = blockIdx.x * blockDim.x + threadIdx.x;
    if (t >= NE) return;
    int s = ei[t];
    int d = ei[NE + t];
    int pos = atomicAdd(&cursor[d], 1);
    float w = dinv[s] * dinv[d];
    erec[pos] = make_int2(s, __float_as_int(w));
}

// ---------------- register-tiled fp32 GEMM ----------------
template<int BM, int BN, int BK, int TM, int TN>
__global__ void gemm_f32(const float* __restrict__ A, const float* __restrict__ B,
                         float* __restrict__ C, int M, int N, int K) {
    constexpr int THREADS = (BM / TM) * (BN / TN);
    __shared__ float sA[BK][BM + 1];
    __shared__ float sB[BK][BN];
    const int tid  = threadIdx.x;
    const int tcol = tid % (BN / TN);
    const int trow = tid / (BN / TN);
    const int row0 = blockIdx.y * BM;
    const int col0 = blockIdx.x * BN;

    float acc[TM][TN];
    #pragma unroll
    for (int i = 0; i < TM; ++i)
        #pragma unroll
        for (int j = 0; j < TN; ++j) acc[i][j] = 0.f;

    for (int k0 = 0; k0 < K; k0 += BK) {
        #pragma unroll
        for (int idx = tid; idx < BM * BK; idx += THREADS) {
            int m = idx / BK, kk = idx % BK;
            int r = row0 + m;
            sA[kk][m] = (r < M) ? A[(size_t)r * K + k0 + kk] : 0.f;
        }
        #pragma unroll
        for (int idx = tid; idx < BK * BN; idx += THREADS) {
            int kk = idx / BN, n = idx % BN;
            int c = col0 + n;
            sB[kk][n] = (c < N) ? B[(size_t)(k0 + kk) * N + c] : 0.f;
        }
        __syncthreads();
        #pragma unroll
        for (int kk = 0; kk < BK; ++kk) {
            float a[TM], b[TN];
            #pragma unroll
            for (int i = 0; i < TM; ++i) a[i] = sA[kk][trow * TM + i];
            #pragma unroll
            for (int j = 0; j < TN; ++j) b[j] = sB[kk][tcol * TN + j];
            #pragma unroll
            for (int i = 0; i < TM; ++i)
                #pragma unroll
                for (int j = 0; j < TN; ++j) acc[i][j] += a[i] * b[j];
        }
        __syncthreads();
    }

    #pragma unroll
    for (int i = 0; i < TM; ++i) {
        int r = row0 + trow * TM + i;
        if (r >= M) continue;
        #pragma unroll
        for (int j = 0; j < TN; ++j) {
            int c = col0 + tcol * TN + j;
            if (c < N) C[(size_t)r * N + c] = acc[i][j];
        }
    }
}

// ---------------- layer-1 gather: one wave per dst node, fused self+bias+relu ----------------
__global__ void agg1_gather(const int* __restrict__ offsets, const int2* __restrict__ erec,
                            const float* __restrict__ dinv, const float* __restrict__ H,
                            const float* __restrict__ b1, float* __restrict__ Hagg) {
    int gw = (blockIdx.x * blockDim.x + threadIdx.x) >> 6;   // node
    if (gw >= NN) return;
    int lane = threadIdx.x & 63;
    int beg = offsets[gw], end = offsets[gw + 1];
    float2 acc = make_float2(0.f, 0.f);
    for (int p = beg; p < end; ++p) {
        int2 r = erec[p];                       // wave-uniform address -> broadcast
        float w = __int_as_float(r.y);
        float2 hv = *reinterpret_cast<const float2*>(H + (size_t)r.x * NH + lane * 2);
        acc.x += hv.x * w;
        acc.y += hv.y * w;
    }
    float di = dinv[gw];
    float sl = di * di;
    float2 hs = *reinterpret_cast<const float2*>(H + (size_t)gw * NH + lane * 2);
    float2 bb = *reinterpret_cast<const float2*>(b1 + lane * 2);
    acc.x = fmaxf(acc.x + hs.x * sl + bb.x, 0.f);
    acc.y = fmaxf(acc.y + hs.y * sl + bb.y, 0.f);
    *reinterpret_cast<float2*>(Hagg + (size_t)gw * NH + lane * 2) = acc;
}

// ---------------- layer-2 gather + self + bias + log_softmax, one wave per node ----------------
__global__ void agg2_lsm(const int* __restrict__ offsets, const int2* __restrict__ erec,
                         const float* __restrict__ dinv, const float* __restrict__ H2,
                         const float* __restrict__ b2, float* __restrict__ out) {
    int node = (blockIdx.x * blockDim.x + threadIdx.x) >> 6;
    if (node >= NN) return;
    int lane = threadIdx.x & 63;
    int beg = offsets[node], end = offsets[node + 1];
    float acc = 0.f;
    for (int p = beg; p < end; ++p) {
        int2 r = erec[p];
        float w = __int_as_float(r.y);
        if (lane < NC) acc += H2[(size_t)r.x * NC + lane] * w;
    }
    float di = dinv[node];
    float v = -INFINITY;
    if (lane < NC) v = acc + H2[(size_t)node * NC + lane] * di * di + b2[lane];
    float m = v;
    #pragma unroll
    for (int off = 32; off; off >>= 1) m = fmaxf(m, __shfl_xor(m, off, 64));
    float ex = (lane < NC) ? expf(v - m) : 0.f;
    #pragma unroll
    for (int off = 32; off; off >>= 1) ex += __shfl_xor(ex, off, 64);
    float ls = logf(ex);
    if (lane < NC) out[(size_t)node * NC + lane] = v - m - ls;
}

extern "C" void kernel_launch(void* const* d_in, const int* in_sizes, int n_in,
                              void* d_out, int out_size, void* d_ws, size_t ws_size,
                              hipStream_t stream) {
    const float* x  = (const float*)d_in[0];
    const int*   ei = (const int*)d_in[1];    // [2, NE]: row 0 = src, row 1 = dst
    const float* W1 = (const float*)d_in[2];
    const float* b1 = (const float*)d_in[3];
    const float* W2 = (const float*)d_in[4];
    const float* b2 = (const float*)d_in[5];
    float* out = (float*)d_out;

    int*   counts  = (int*)d_ws;
    int*   offsets = counts + OFF_OFFSETS;
    int*   cursor  = counts + OFF_CURSOR;
    float* dinv    = (float*)(counts + OFF_DINV);
    int2*  erec    = (int2*)(counts + OFF_EREC);
    float* H       = (float*)(counts + OFF_H);
    float* Hagg    = (float*)(counts + OFF_HAGG);
    float* H2      = H;                        // reuse: H dead after agg1_gather

    // 1. CSR build
    hipMemsetAsync(counts, 0, NN * sizeof(int), stream);
    count_kernel<<<(NE + 255) / 256, 256, 0, stream>>>(ei + NE, counts);
    dinv_kernel<<<(NN + 255) / 256, 256, 0, stream>>>(counts, dinv);
    scan_kernel<<<1, 1024, 0, stream>>>(counts, offsets, cursor);
    bucket_kernel<<<(NE + 255) / 256, 256, 0, stream>>>(ei, dinv, cursor, erec);

    // 2. H = x @ W1
    {
        dim3 grid((NH + 63) / 64, (NN + 63) / 64);
        gemm_f32<64, 64, 16, 4, 4><<<grid, 256, 0, stream>>>(x, W1, H, NN, NH, NF);
    }

    // 3. layer-1 gather (fused self-loop + bias + relu) -> Hagg
    {
        long long threads = (long long)NN * 64;
        agg1_gather<<<(unsigned)((threads + 255) / 256), 256, 0, stream>>>(
            offsets, erec, dinv, H, b1, Hagg);
    }

    // 4. H2 = Hagg @ W2
    {
        dim3 grid((NC + 63) / 64, (NN + 63) / 64);
        gemm_f32<64, 64, 16, 4, 4><<<grid, 256, 0, stream>>>(Hagg, W2, H2, NN, NC, NH);
    }

    // 5. layer-2 gather + self + bias + log_softmax -> out
    {
        long long threads = (long long)NN * 64;
        agg2_lsm<<<(unsigned)((threads + 255) / 256), 256, 0, stream>>>(
            offsets, erec, dinv, H2, b2, out);
    }
}

// Round 3
// 803.705 us; speedup vs baseline: 4.2641x; 1.2628x over previous
//
#include <hip/hip_runtime.h>
#include <hip/hip_bf16.h>
#include <math.h>

#define NN 100000      // nodes
#define NE 1600000     // edges
#define NF 256         // input features
#define NH 128         // hidden
#define NC 40          // classes

// Workspace layout (4-byte units):
//   counts  [0,       100032)
//   offsets [100032,  200128)   (NN+1 used)
//   cursor  [200128,  300160)
//   dinv    [300160,  400192)
//   erec    [400192,  3600192)  (NE int2)
//   H       [3600192, 16400192) (NN*NH floats; scan scratch before gemm1; reused as H2 after agg1)
//   Hagg    [16400192,29200192) (NN*NH floats)
#define OFF_OFFSETS 100032
#define OFF_CURSOR  200128
#define OFF_DINV    300160
#define OFF_EREC    400192
#define OFF_H       3600192
#define OFF_HAGG    16400192

#define SCAN_TILE 1024
#define SCAN_NB   ((NN + SCAN_TILE - 1) / SCAN_TILE)   // 98

// ---------------- CSR build ----------------
__global__ void count_kernel(const int* __restrict__ dst, int* __restrict__ count) {
    int t = blockIdx.x * blockDim.x + threadIdx.x;
    if (t < NE) atomicAdd(&count[dst[t]], 1);
}

__global__ void dinv_kernel(const int* __restrict__ count, float* __restrict__ dinv) {
    int t = blockIdx.x * blockDim.x + threadIdx.x;
    if (t < NN) dinv[t] = rsqrtf((float)count[t] + 1.0f);  // +1 self loop
}

// ---- hierarchical scan: phase 1 — per-tile reduce ----
__global__ void scan_phase1(const int* __restrict__ count, int* __restrict__ blocksums) {
    int b = blockIdx.x, t = threadIdx.x;
    int i = b * SCAN_TILE + t;
    int v = (i < NN) ? count[i] : 0;
    #pragma unroll
    for (int off = 32; off; off >>= 1) v += __shfl_xor(v, off, 64);
    __shared__ int ws[16];
    int lane = t & 63, wave = t >> 6;
    if (lane == 0) ws[wave] = v;
    __syncthreads();
    if (t == 0) {
        int s = 0;
        #pragma unroll
        for (int w = 0; w < SCAN_TILE / 64; ++w) s += ws[w];
        blocksums[b] = s;
    }
}

// ---- phase 2 — scan the 98 block sums (one small block) ----
__global__ void scan_phase2(const int* __restrict__ blocksums, int* __restrict__ blockpref) {
    __shared__ int s[128];
    int t = threadIdx.x;
    int v = (t < SCAN_NB) ? blocksums[t] : 0;
    s[t] = v;
    __syncthreads();
    for (int off = 1; off < 128; off <<= 1) {
        int u = (t >= off) ? s[t - off] : 0;
        __syncthreads();
        s[t] += u;
        __syncthreads();
    }
    if (t < SCAN_NB) blockpref[t] = s[t] - v;   // exclusive prefix
}

// ---- phase 3 — in-tile exclusive scan + block prefix -> offsets & cursor ----
__global__ void scan_phase3(const int* __restrict__ count, const int* __restrict__ blockpref,
                            int* __restrict__ offsets, int* __restrict__ cursor) {
    int b = blockIdx.x, t = threadIdx.x;
    int i = b * SCAN_TILE + t;
    int v = (i < NN) ? count[i] : 0;
    int lane = t & 63, wave = t >> 6;
    // inclusive wave scan
    int s = v;
    #pragma unroll
    for (int off = 1; off < 64; off <<= 1) {
        int u = __shfl_up(s, off, 64);
        if (lane >= off) s += u;
    }
    __shared__ int wsum[16];
    if (lane == 63) wsum[wave] = s;
    __syncthreads();
    if (t < 16) {
        int x = wsum[t];
        #pragma unroll
        for (int off = 1; off < 16; off <<= 1) {
            int u = __shfl_up(x, off, 64);
            if (t >= off) x += u;
        }
        wsum[t] = x;   // inclusive scan of wave sums
    }
    __syncthreads();
    int excl = (s - v) + (wave ? wsum[wave - 1] : 0) + blockpref[b];
    if (i < NN) {
        offsets[i] = excl;
        cursor[i]  = excl;
        if (i == NN - 1) offsets[NN] = excl + v;
    }
}

// counting-sort edges into dst buckets; record (src, weight)
__global__ void bucket_kernel(const int* __restrict__ ei, const float* __restrict__ dinv,
                              int* __restrict__ cursor, int2* __restrict__ erec) {
    int t = blockIdx.x * blockDim.x + threadIdx.x;
    if (t >= NE) return;
    int s = ei[t];
    int d = ei[NE + t];
    int pos = atomicAdd(&cursor[d], 1);
    float w = dinv[s] * dinv[d];
    erec[pos] = make_int2(s, __float_as_int(w));
}

// ---------------- register-tiled fp32 GEMM ----------------
template<int BM, int BN, int BK, int TM, int TN>
__global__ void gemm_f32(const float* __restrict__ A, const float* __restrict__ B,
                         float* __restrict__ C, int M, int N, int K) {
    constexpr int THREADS = (BM / TM) * (BN / TN);
    __shared__ float sA[BK][BM + 1];
    __shared__ float sB[BK][BN];
    const int tid  = threadIdx.x;
    const int tcol = tid % (BN / TN);
    const int trow = tid / (BN / TN);
    const int row0 = blockIdx.y * BM;
    const int col0 = blockIdx.x * BN;

    float acc[TM][TN];
    #pragma unroll
    for (int i = 0; i < TM; ++i)
        #pragma unroll
        for (int j = 0; j < TN; ++j) acc[i][j] = 0.f;

    for (int k0 = 0; k0 < K; k0 += BK) {
        #pragma unroll
        for (int idx = tid; idx < BM * BK; idx += THREADS) {
            int m = idx / BK, kk = idx % BK;
            int r = row0 + m;
            sA[kk][m] = (r < M) ? A[(size_t)r * K + k0 + kk] : 0.f;
        }
        #pragma unroll
        for (int idx = tid; idx < BK * BN; idx += THREADS) {
            int kk = idx / BN, n = idx % BN;
            int c = col0 + n;
            sB[kk][n] = (c < N) ? B[(size_t)(k0 + kk) * N + c] : 0.f;
        }
        __syncthreads();
        #pragma unroll
        for (int kk = 0; kk < BK; ++kk) {
            float a[TM], b[TN];
            #pragma unroll
            for (int i = 0; i < TM; ++i) a[i] = sA[kk][trow * TM + i];
            #pragma unroll
            for (int j = 0; j < TN; ++j) b[j] = sB[kk][tcol * TN + j];
            #pragma unroll
            for (int i = 0; i < TM; ++i)
                #pragma unroll
                for (int j = 0; j < TN; ++j) acc[i][j] += a[i] * b[j];
        }
        __syncthreads();
    }

    #pragma unroll
    for (int i = 0; i < TM; ++i) {
        int r = row0 + trow * TM + i;
        if (r >= M) continue;
        #pragma unroll
        for (int j = 0; j < TN; ++j) {
            int c = col0 + tcol * TN + j;
            if (c < N) C[(size_t)r * N + c] = acc[i][j];
        }
    }
}

// ---------------- layer-1 gather: one wave per dst node, fused self+bias+relu ----------------
__global__ void agg1_gather(const int* __restrict__ offsets, const int2* __restrict__ erec,
                            const float* __restrict__ dinv, const float* __restrict__ H,
                            const float* __restrict__ b1, float* __restrict__ Hagg) {
    int gw = (blockIdx.x * blockDim.x + threadIdx.x) >> 6;   // node
    if (gw >= NN) return;
    int lane = threadIdx.x & 63;
    int beg = offsets[gw], end = offsets[gw + 1];
    float2 acc = make_float2(0.f, 0.f);
    for (int p = beg; p < end; ++p) {
        int2 r = erec[p];                       // wave-uniform address -> broadcast
        float w = __int_as_float(r.y);
        float2 hv = *reinterpret_cast<const float2*>(H + (size_t)r.x * NH + lane * 2);
        acc.x += hv.x * w;
        acc.y += hv.y * w;
    }
    float di = dinv[gw];
    float sl = di * di;
    float2 hs = *reinterpret_cast<const float2*>(H + (size_t)gw * NH + lane * 2);
    float2 bb = *reinterpret_cast<const float2*>(b1 + lane * 2);
    acc.x = fmaxf(acc.x + hs.x * sl + bb.x, 0.f);
    acc.y = fmaxf(acc.y + hs.y * sl + bb.y, 0.f);
    *reinterpret_cast<float2*>(Hagg + (size_t)gw * NH + lane * 2) = acc;
}

// ---------------- layer-2 gather + self + bias + log_softmax, one wave per node ----------------
__global__ void agg2_lsm(const int* __restrict__ offsets, const int2* __restrict__ erec,
                         const float* __restrict__ dinv, const float* __restrict__ H2,
                         const float* __restrict__ b2, float* __restrict__ out) {
    int node = (blockIdx.x * blockDim.x + threadIdx.x) >> 6;
    if (node >= NN) return;
    int lane = threadIdx.x & 63;
    int beg = offsets[node], end = offsets[node + 1];
    float acc = 0.f;
    for (int p = beg; p < end; ++p) {
        int2 r = erec[p];
        float w = __int_as_float(r.y);
        if (lane < NC) acc += H2[(size_t)r.x * NC + lane] * w;
    }
    float di = dinv[node];
    float v = -INFINITY;
    if (lane < NC) v = acc + H2[(size_t)node * NC + lane] * di * di + b2[lane];
    float m = v;
    #pragma unroll
    for (int off = 32; off; off >>= 1) m = fmaxf(m, __shfl_xor(m, off, 64));
    float ex = (lane < NC) ? expf(v - m) : 0.f;
    #pragma unroll
    for (int off = 32; off; off >>= 1) ex += __shfl_xor(ex, off, 64);
    float ls = logf(ex);
    if (lane < NC) out[(size_t)node * NC + lane] = v - m - ls;
}

extern "C" void kernel_launch(void* const* d_in, const int* in_sizes, int n_in,
                              void* d_out, int out_size, void* d_ws, size_t ws_size,
                              hipStream_t stream) {
    const float* x  = (const float*)d_in[0];
    const int*   ei = (const int*)d_in[1];    // [2, NE]: row 0 = src, row 1 = dst
    const float* W1 = (const float*)d_in[2];
    const float* b1 = (const float*)d_in[3];
    const float* W2 = (const float*)d_in[4];
    const float* b2 = (const float*)d_in[5];
    float* out = (float*)d_out;

    int*   counts  = (int*)d_ws;
    int*   offsets = counts + OFF_OFFSETS;
    int*   cursor  = counts + OFF_CURSOR;
    float* dinv    = (float*)(counts + OFF_DINV);
    int2*  erec    = (int2*)(counts + OFF_EREC);
    float* H       = (float*)(counts + OFF_H);
    float* Hagg    = (float*)(counts + OFF_HAGG);
    float* H2      = H;                        // reuse: H dead after agg1_gather

    // scan scratch inside H region (H not written until gemm1, which runs later)
    int* blocksums = (int*)H;          // [98]
    int* blockpref = (int*)H + 128;    // [98]

    // 1. CSR build
    hipMemsetAsync(counts, 0, NN * sizeof(int), stream);
    count_kernel<<<(NE + 255) / 256, 256, 0, stream>>>(ei + NE, counts);
    dinv_kernel<<<(NN + 255) / 256, 256, 0, stream>>>(counts, dinv);
    scan_phase1<<<SCAN_NB, SCAN_TILE, 0, stream>>>(counts, blocksums);
    scan_phase2<<<1, 128, 0, stream>>>(blocksums, blockpref);
    scan_phase3<<<SCAN_NB, SCAN_TILE, 0, stream>>>(counts, blockpref, offsets, cursor);
    bucket_kernel<<<(NE + 255) / 256, 256, 0, stream>>>(ei, dinv, cursor, erec);

    // 2. H = x @ W1
    {
        dim3 grid((NH + 63) / 64, (NN + 63) / 64);
        gemm_f32<64, 64, 16, 4, 4><<<grid, 256, 0, stream>>>(x, W1, H, NN, NH, NF);
    }

    // 3. layer-1 gather (fused self-loop + bias + relu) -> Hagg
    {
        long long threads = (long long)NN * 64;
        agg1_gather<<<(unsigned)((threads + 255) / 256), 256, 0, stream>>>(
            offsets, erec, dinv, H, b1, Hagg);
    }

    // 4. H2 = Hagg @ W2
    {
        dim3 grid((NC + 63) / 64, (NN + 63) / 64);
        gemm_f32<64, 64, 16, 4, 4><<<grid, 256, 0, stream>>>(Hagg, W2, H2, NN, NC, NH);
    }

    // 5. layer-2 gather + self + bias + log_softmax -> out
    {
        long long threads = (long long)NN * 64;
        agg2_lsm<<<(unsigned)((threads + 255) / 256), 256, 0, stream>>>(
            offsets, erec, dinv, H2, b2, out);
    }
}